// Round 18
// baseline (98.567 us; speedup 1.0000x reference)
//
#include <hip/hip_runtime.h>

#define NN 50000
#define NE 800000
#define DIN 128
#define DH 200
#define DHP 256   // padded hidden
#define DO 64
#define RPB 32        // rows per bucket
#define NBUCK 1564    // ceil(NN/32)
#define CAP 1024      // bucket capacity; lambda=512, sigma=22.6 -> +22 sigma
#define EPB 8192      // edges per histogram/scatter block (512 thr x 16)
#define NBLK_E ((NE + EPB - 1) / EPB)   // 98
#define CVT_B 1563    // ceil(800000/512), 8 floats/thread
#define PACK_B 12     // 6144/512
#define NBIN 256      // row*8 + (col>>13): col-phase sub-bins

typedef float f32x4 __attribute__((ext_vector_type(4)));
typedef short bf16x8 __attribute__((ext_vector_type(8)));
typedef short s16x4 __attribute__((ext_vector_type(4)));
typedef unsigned int uint;

__device__ __forceinline__ unsigned short f2bf(float f) {
  unsigned int b = __float_as_uint(f);
  b = (b + 0x7FFFu + ((b >> 16) & 1u)) >> 16;
  return (unsigned short)b;
}
__device__ __forceinline__ float bf2f(unsigned short u) {
  return __uint_as_float((unsigned int)u << 16);
}

// ---------------- prep: cvt x->bf16 | block-local histogram | pack W -------
// hist is BUCKET-MAJOR: hist[k][b] (k = bucket, b = edge-block). The strided
// writes here are latency-hidden by thousands of waves; the scan then reads
// each bucket's 98 counts CONTIGUOUSLY.
__global__ __launch_bounds__(512) void k_prep(const float* __restrict__ x,
                                              uint* __restrict__ xb,
                                              const int* __restrict__ row,
                                              int* __restrict__ hist,
                                              const float* __restrict__ W1,
                                              const float* __restrict__ W2,
                                              unsigned short* __restrict__ B1p,
                                              unsigned short* __restrict__ B2p) {
  __shared__ int lh[NBUCK];
  const int bid = blockIdx.x;
  const int tid = threadIdx.x;
  if (bid < CVT_B) {
    int i = bid * 512 + tid;
    if (i < NN * DIN / 8) {  // 800000 cvt work items (8 floats each)
      f32x4 a = *reinterpret_cast<const f32x4*>(x + (size_t)i * 8);
      f32x4 b = *reinterpret_cast<const f32x4*>(x + (size_t)i * 8 + 4);
      uint4 o;
      o.x = (uint)f2bf(a[0]) | ((uint)f2bf(a[1]) << 16);
      o.y = (uint)f2bf(a[2]) | ((uint)f2bf(a[3]) << 16);
      o.z = (uint)f2bf(b[0]) | ((uint)f2bf(b[1]) << 16);
      o.w = (uint)f2bf(b[2]) | ((uint)f2bf(b[3]) << 16);
      *reinterpret_cast<uint4*>(xb + (size_t)i * 4) = o;
    }
  } else if (bid < CVT_B + NBLK_E) {
    const int hb = bid - CVT_B;
    const int e0 = hb * EPB;
    for (int j = tid; j < NBUCK; j += 512) lh[j] = 0;
    __syncthreads();
#pragma unroll
    for (int p = 0; p < EPB / 512; ++p) {
      int e = e0 + p * 512 + tid;
      if (e < NE) atomicAdd(&lh[row[e] >> 5], 1);
    }
    __syncthreads();
    for (int j = tid; j < NBUCK; j += 512)
      hist[(size_t)j * NBLK_E + hb] = lh[j];   // bucket-major
  } else {
    int gidx = (bid - CVT_B - NBLK_E) * 512 + tid;  // 6144 total
    if (gidx < 4096) {
      int idx = gidx;
      int lane = idx & 63;
      int s = (idx >> 6) & 3;
      int t = idx >> 8;
      int n = t * 16 + (lane & 15);
      unsigned short v[8];
#pragma unroll
      for (int j = 0; j < 8; ++j) {
        int k = s * 32 + (j & 3) + ((lane >> 4) << 2) + ((j >> 2) << 4);
        float f = (n < DH) ? W1[(size_t)k * DH + n] : 0.f;
        v[j] = f2bf(f);
      }
      *reinterpret_cast<uint4*>(B1p + (size_t)idx * 8) =
          *reinterpret_cast<const uint4*>(v);
    } else if (gidx < 6144) {
      int idx = gidx - 4096;
      int lane = idx & 63;
      int s = (idx >> 6) & 7;
      int t = idx >> 9;
      int n = t * 16 + (lane & 15);
      unsigned short v[8];
#pragma unroll
      for (int j = 0; j < 8; ++j) {
        int k = s * 32 + (j & 3) + ((lane >> 4) << 2) + ((j >> 2) << 4);
        float f = (k < DH) ? W2[(size_t)k * DO + n] : 0.f;
        v[j] = f2bf(f);
      }
      *reinterpret_cast<uint4*>(B2p + (size_t)idx * 8) =
          *reinterpret_cast<const uint4*>(v);
    }
  }
}

// ---------------- scan: thread k owns bucket k; contiguous serial prefix ---
// hist[k][0..98): 392 consecutive bytes per thread, all L2-resident.
__global__ __launch_bounds__(256) void k_scan(int* __restrict__ hist,
                                              int* __restrict__ cnt) {
  int k = blockIdx.x * 256 + threadIdx.x;
  if (k >= NBUCK) return;
  int* hk = hist + (size_t)k * NBLK_E;
  int run = 0;
#pragma unroll 2
  for (int b = 0; b < NBLK_E; b += 2) {   // NBLK_E = 98, even
    int v0 = hk[b], v1 = hk[b + 1];
    hk[b] = run; run += v0;
    hk[b + 1] = run; run += v1;
  }
  cnt[k] = run;
}

// ---------------- phase C: rank + scatter (single-writer segments) ---------
__global__ __launch_bounds__(512) void k_scatC(const int* __restrict__ row,
                                               const int* __restrict__ col,
                                               const float* __restrict__ val,
                                               const int* __restrict__ hist,
                                               uint2* __restrict__ ep) {
  __shared__ int lh[NBUCK];
  __shared__ int lbase[NBUCK];
  const int tid = threadIdx.x;
  const int e0 = blockIdx.x * EPB;
  for (int j = tid; j < NBUCK; j += 512) {
    lh[j] = 0;
    lbase[j] = hist[(size_t)j * NBLK_E + blockIdx.x];  // bucket-major read
  }
  __syncthreads();
#pragma unroll
  for (int p = 0; p < EPB / 512; ++p) {
    int e = e0 + p * 512 + tid;
    if (e < NE) {
      int r = row[e];
      int k = r >> 5;
      int rank = atomicAdd(&lh[k], 1);
      int pos = lbase[k] + rank;
      if (pos < CAP)
        ep[(size_t)k * CAP + pos] =
            make_uint2((uint)col[e] | ((uint)(r & (RPB - 1)) << 16),
                       __float_as_uint(val[e]));
    }
  }
}

// ---------------- fused SpMM + MLP: one block per 32-row bucket ------------
// (round-14 proven body, 43.4 us) 256 thr (4 waves); in-LDS counting sort
// by (row, col>>13); half-wave paired gather; MFMA MLP; LDS aliasing.
__global__ __launch_bounds__(256, 8) void k_spmm_mlp(const uint* __restrict__ xbu,
                                                     const uint2* __restrict__ ep,
                                                     const int* __restrict__ cnt,
                                                     const unsigned short* __restrict__ B1p,
                                                     const float* __restrict__ b1,
                                                     const unsigned short* __restrict__ B2p,
                                                     const float* __restrict__ b2,
                                                     float* __restrict__ out) {
  __shared__ uint2 buf2[2112];  // 16896 B
  __shared__ int deg2[NBIN], rbase2[NBIN], rpos2[NBIN];
  __shared__ int ws[4];
  uint2* se = buf2;                                       // [CAP]   8192 B
  unsigned short* hb = (unsigned short*)(buf2 + CAP);     // [32][136] 8704 B
  unsigned short* hs = (unsigned short*)buf2;             // [32][260] 16640 B (aliases se+hb)
  const int tid = threadIdx.x;
  const int bucket = blockIdx.x;
  const int r0 = bucket * RPB;
  const int w = tid >> 6, lane = tid & 63;
  const int g = lane >> 4, r16 = lane & 15;
  const int half = lane >> 5, l32 = lane & 31;

  deg2[tid] = 0;
  __syncthreads();

  int n = cnt[bucket];
  if (n > CAP) n = CAP;
  const uint2* eb = ep + (size_t)bucket * CAP;

  // load this bucket's records once into registers (4 per thread)
  uint2 rec[4];
  int key[4];
#pragma unroll
  for (int q = 0; q < 4; ++q) {
    int j = q * 256 + tid;
    rec[q] = (j < n) ? eb[j] : make_uint2(0u, 0u);
    key[q] = (int)(((rec[q].x >> 16) & (RPB - 1)) * 8 + ((rec[q].x & 0xFFFFu) >> 13));
  }
  // pass 1: per-bin counts
#pragma unroll
  for (int q = 0; q < 4; ++q)
    if (q * 256 + tid < n) atomicAdd(&deg2[key[q]], 1);
  __syncthreads();

  // block-wide exclusive scan of 256 bin counts
  {
    int v = deg2[tid];
    int incl = v;
#pragma unroll
    for (int d = 1; d < 64; d <<= 1) {
      int t = __shfl_up(incl, d, 64);
      if (lane >= d) incl += t;
    }
    if (lane == 63) ws[w] = incl;
    __syncthreads();
    if (tid == 0) {
      int s = 0;
#pragma unroll
      for (int q = 0; q < 4; ++q) { int xx = ws[q]; ws[q] = s; s += xx; }
    }
    __syncthreads();
    int excl = ws[w] + incl - v;
    rbase2[tid] = excl;
    rpos2[tid] = excl;
  }
  __syncthreads();

  // pass 2: scatter records (row, col-window)-sorted into LDS
#pragma unroll
  for (int q = 0; q < 4; ++q)
    if (q * 256 + tid < n) {
      int p = atomicAdd(&rpos2[key[q]], 1);
      se[p] = make_uint2(rec[q].x & 0xFFFFu, rec[q].y);
    }
  __syncthreads();

  // gather: wave w owns rows w, w+4, ..., w+28; half-wave edge pairing,
  // each lane loads uint2 = 4 bf16 features.
  const uint2* xb2 = reinterpret_cast<const uint2*>(xbu);
  for (int rr = w; rr < RPB; rr += 4) {
    int gr = r0 + rr;
    if (gr >= NN) {
      if (half == 0)
        *reinterpret_cast<uint2*>(&hb[rr * 136 + 4 * l32]) = make_uint2(0u, 0u);
      continue;
    }
    int s = rbase2[rr * 8];
    int en = (rr < RPB - 1) ? rbase2[(rr + 1) * 8] : n;
    float a0 = 0.f, a1 = 0.f, a2 = 0.f, a3 = 0.f;
    int j = s + half;
    for (; j + 6 < en; j += 8) {
      uint2 e[4], qv[4];
#pragma unroll
      for (int t = 0; t < 4; ++t) e[t] = se[j + 2 * t];
#pragma unroll
      for (int t = 0; t < 4; ++t) qv[t] = xb2[(size_t)e[t].x * 32 + l32];
#pragma unroll
      for (int t = 0; t < 4; ++t) {
        float v = __uint_as_float(e[t].y);
        a0 += v * bf2f((unsigned short)qv[t].x);
        a1 += v * bf2f((unsigned short)(qv[t].x >> 16));
        a2 += v * bf2f((unsigned short)qv[t].y);
        a3 += v * bf2f((unsigned short)(qv[t].y >> 16));
      }
    }
    for (; j < en; j += 2) {
      uint2 e0 = se[j];
      uint2 q0 = xb2[(size_t)e0.x * 32 + l32];
      float v0 = __uint_as_float(e0.y);
      a0 += v0 * bf2f((unsigned short)q0.x);
      a1 += v0 * bf2f((unsigned short)(q0.x >> 16));
      a2 += v0 * bf2f((unsigned short)q0.y);
      a3 += v0 * bf2f((unsigned short)(q0.y >> 16));
    }
    // merge the two half-wave partials
    a0 += __shfl_xor(a0, 32, 64);
    a1 += __shfl_xor(a1, 32, 64);
    a2 += __shfl_xor(a2, 32, 64);
    a3 += __shfl_xor(a3, 32, 64);
    // + x self
    uint2 xs = xb2[(size_t)gr * 32 + l32];
    a0 += bf2f((unsigned short)xs.x);
    a1 += bf2f((unsigned short)(xs.x >> 16));
    a2 += bf2f((unsigned short)xs.y);
    a3 += bf2f((unsigned short)(xs.y >> 16));
    if (half == 0) {
      uint2 o;
      o.x = (uint)f2bf(a0) | ((uint)f2bf(a1) << 16);
      o.y = (uint)f2bf(a2) | ((uint)f2bf(a3) << 16);
      *reinterpret_cast<uint2*>(&hb[rr * 136 + 4 * l32]) = o;
    }
  }
  __syncthreads();   // hb ready; se dead from here on

  // ---- stage 1: hs = relu(hb @ W1 + b1); wave w = n-tiles w*4..w*4+3 ------
  f32x4 acc[2][4];
#pragma unroll
  for (int a = 0; a < 2; ++a)
#pragma unroll
    for (int b = 0; b < 4; ++b)
#pragma unroll
      for (int c = 0; c < 4; ++c) acc[a][b][c] = 0.f;

  for (int s = 0; s < 4; ++s) {
    bf16x8 af[2];
#pragma unroll
    for (int mr = 0; mr < 2; ++mr) {
      const unsigned short* p = &hb[(mr * 16 + r16) * 136 + s * 32 + g * 4];
      s16x4 lo4 = *reinterpret_cast<const s16x4*>(p);
      s16x4 hi4 = *reinterpret_cast<const s16x4*>(p + 16);
#pragma unroll
      for (int j = 0; j < 4; ++j) { af[mr][j] = lo4[j]; af[mr][4 + j] = hi4[j]; }
    }
#pragma unroll
    for (int nr = 0; nr < 4; ++nr) {
      int t = w * 4 + nr;
      bf16x8 bf = *reinterpret_cast<const bf16x8*>(B1p + (size_t)((t * 4 + s) * 64 + lane) * 8);
      acc[0][nr] = __builtin_amdgcn_mfma_f32_16x16x32_bf16(af[0], bf, acc[0][nr], 0, 0, 0);
      acc[1][nr] = __builtin_amdgcn_mfma_f32_16x16x32_bf16(af[1], bf, acc[1][nr], 0, 0, 0);
    }
  }
  __syncthreads();   // all hb reads done; hs may now overwrite se+hb
#pragma unroll
  for (int mr = 0; mr < 2; ++mr)
#pragma unroll
    for (int nr = 0; nr < 4; ++nr) {
      int nn = w * 64 + nr * 16 + r16;
      float bias = (nn < DH) ? b1[nn] : 0.f;
#pragma unroll
      for (int i = 0; i < 4; ++i) {
        int rl = mr * 16 + g * 4 + i;
        float v = acc[mr][nr][i] + bias;
        v = v > 0.f ? v : 0.f;
        if (nn >= DH) v = 0.f;
        hs[rl * 260 + nn] = f2bf(v);
      }
    }
  __syncthreads();

  // ---- stage 2: out = hs @ W2 + b2; wave w = n-tile w, m-tiles 0..1 -------
  f32x4 acc2[2];
#pragma unroll
  for (int b = 0; b < 2; ++b)
#pragma unroll
    for (int c = 0; c < 4; ++c) acc2[b][c] = 0.f;

  for (int s = 0; s < 8; ++s) {
#pragma unroll
    for (int mt = 0; mt < 2; ++mt) {
      const unsigned short* p = &hs[(mt * 16 + r16) * 260 + s * 32 + g * 4];
      s16x4 lo4 = *reinterpret_cast<const s16x4*>(p);
      s16x4 hi4 = *reinterpret_cast<const s16x4*>(p + 16);
      bf16x8 af;
#pragma unroll
      for (int j = 0; j < 4; ++j) { af[j] = lo4[j]; af[4 + j] = hi4[j]; }
      bf16x8 bf = *reinterpret_cast<const bf16x8*>(B2p + (size_t)((w * 8 + s) * 64 + lane) * 8);
      acc2[mt] = __builtin_amdgcn_mfma_f32_16x16x32_bf16(af, bf, acc2[mt], 0, 0, 0);
    }
  }
#pragma unroll
  for (int mt = 0; mt < 2; ++mt) {
    int nn = w * 16 + r16;
    float bias = b2[nn];
#pragma unroll
    for (int i = 0; i < 4; ++i) {
      int grow = r0 + mt * 16 + g * 4 + i;
      if (grow < NN) out[(size_t)grow * DO + nn] = acc2[mt][i] + bias;
    }
  }
}

extern "C" void kernel_launch(void* const* d_in, const int* in_sizes, int n_in,
                              void* d_out, int out_size, void* d_ws, size_t ws_size,
                              hipStream_t stream) {
  const float* x = (const float*)d_in[0];
  const int* erow = (const int*)d_in[1];
  const int* ecol = (const int*)d_in[2];
  const float* eval_ = (const float*)d_in[3];
  const float* W1 = (const float*)d_in[4];
  const float* b1 = (const float*)d_in[5];
  const float* W2 = (const float*)d_in[6];
  const float* b2 = (const float*)d_in[7];
  float* out = (float*)d_out;

  char* ws = (char*)d_ws;
  size_t o = 0;
  uint* xb = (uint*)(ws + o);          o += (size_t)NN * 64 * 4;   // x bf16, 12.8 MB
  unsigned short* B1p = (unsigned short*)(ws + o); o += 32768 * 2; // 64 KB
  unsigned short* B2p = (unsigned short*)(ws + o); o += 16384 * 2; // 32 KB
  o = (o + 255) & ~(size_t)255;
  int* cnt = (int*)(ws + o);           o += (NBUCK * 4 + 255) & ~(size_t)255;
  int* hist = (int*)(ws + o);          o += (size_t)NBUCK * NBLK_E * 4;  // 613 KB
  o = (o + 255) & ~(size_t)255;
  uint2* ep = (uint2*)(ws + o);        // NBUCK*CAP*8 = 12.8 MB

  k_prep<<<CVT_B + NBLK_E + PACK_B, 512, 0, stream>>>(x, xb, erow, hist, W1, W2, B1p, B2p);
  k_scan<<<(NBUCK + 255) / 256, 256, 0, stream>>>(hist, cnt);
  k_scatC<<<NBLK_E, 512, 0, stream>>>(erow, ecol, eval_, hist, ep);
  k_spmm_mlp<<<NBUCK, 256, 0, stream>>>(xb, ep, cnt, B1p, b1, B2p, b2, out);
}

// Round 19
// 76.571 us; speedup vs baseline: 1.2873x; 1.2873x over previous
//
#include <hip/hip_runtime.h>

#define NN 50000
#define NE 800000
#define DIN 128
#define DH 200
#define DHP 256   // padded hidden
#define DO 64
#define RPB 32        // rows per bucket
#define NBUCK 1564    // ceil(NN/32)
#define CAP 1024      // bucket capacity; lambda=512, sigma=22.6 -> +22 sigma
#define EPB 8192      // edges per histogram/scatter block (512 thr x 16)
#define NBLK_E ((NE + EPB - 1) / EPB)   // 98
#define SCAN_B 7      // ceil(NBUCK/256)
#define CVT_B 3125    // 800000 items / 256
#define PACK_B 24     // 6144 / 256
#define NBIN 256      // row*8 + (col>>13): col-phase sub-bins

typedef float f32x4 __attribute__((ext_vector_type(4)));
typedef short bf16x8 __attribute__((ext_vector_type(8)));
typedef short s16x4 __attribute__((ext_vector_type(4)));
typedef unsigned int uint;

__device__ __forceinline__ unsigned short f2bf(float f) {
  unsigned int b = __float_as_uint(f);
  b = (b + 0x7FFFu + ((b >> 16) & 1u)) >> 16;
  return (unsigned short)b;
}
__device__ __forceinline__ float bf2f(unsigned short u) {
  return __uint_as_float((unsigned int)u << 16);
}

// ---------------- phase A: block-local bucket histogram (block-major) ------
__global__ __launch_bounds__(512) void k_hist(const int* __restrict__ row,
                                              int* __restrict__ hist) {
  __shared__ int lh[NBUCK];
  const int tid = threadIdx.x;
  const int e0 = blockIdx.x * EPB;
  for (int j = tid; j < NBUCK; j += 512) lh[j] = 0;
  __syncthreads();
#pragma unroll
  for (int p = 0; p < EPB / 512; ++p) {
    int e = e0 + p * 512 + tid;
    if (e < NE) atomicAdd(&lh[row[e] >> 5], 1);
  }
  __syncthreads();
  int* hrow = hist + (size_t)blockIdx.x * NBUCK;
  for (int j = tid; j < NBUCK; j += 512) hrow[j] = lh[j];
}

// ---------------- scan (7 blocks) | cvt x->bf16 (3125) | pack W (24) -------
// The 7 latency-bound scan blocks overlap with 3149 streaming blocks.
__global__ __launch_bounds__(256) void k_scan_cvt_pack(
    int* __restrict__ hist, int* __restrict__ cnt,
    const float* __restrict__ x, uint* __restrict__ xb,
    const float* __restrict__ W1, const float* __restrict__ W2,
    unsigned short* __restrict__ B1p, unsigned short* __restrict__ B2p) {
  const int bid = blockIdx.x;
  const int tid = threadIdx.x;
  if (bid < SCAN_B) {
    // serial prefix over edge-blocks for bucket k (strided, 8-wide batches)
    int k = bid * 256 + tid;
    if (k >= NBUCK) return;
    int run = 0;
    int b = 0;
    for (; b + 8 <= NBLK_E; b += 8) {
      int v0 = hist[(size_t)(b + 0) * NBUCK + k];
      int v1 = hist[(size_t)(b + 1) * NBUCK + k];
      int v2 = hist[(size_t)(b + 2) * NBUCK + k];
      int v3 = hist[(size_t)(b + 3) * NBUCK + k];
      int v4 = hist[(size_t)(b + 4) * NBUCK + k];
      int v5 = hist[(size_t)(b + 5) * NBUCK + k];
      int v6 = hist[(size_t)(b + 6) * NBUCK + k];
      int v7 = hist[(size_t)(b + 7) * NBUCK + k];
      hist[(size_t)(b + 0) * NBUCK + k] = run; run += v0;
      hist[(size_t)(b + 1) * NBUCK + k] = run; run += v1;
      hist[(size_t)(b + 2) * NBUCK + k] = run; run += v2;
      hist[(size_t)(b + 3) * NBUCK + k] = run; run += v3;
      hist[(size_t)(b + 4) * NBUCK + k] = run; run += v4;
      hist[(size_t)(b + 5) * NBUCK + k] = run; run += v5;
      hist[(size_t)(b + 6) * NBUCK + k] = run; run += v6;
      hist[(size_t)(b + 7) * NBUCK + k] = run; run += v7;
    }
    for (; b < NBLK_E; ++b) {
      int v = hist[(size_t)b * NBUCK + k];
      hist[(size_t)b * NBUCK + k] = run;
      run += v;
    }
    cnt[k] = run;
  } else if (bid < SCAN_B + CVT_B) {
    int i = (bid - SCAN_B) * 256 + tid;  // 800000 items, 8 floats each
    f32x4 a = *reinterpret_cast<const f32x4*>(x + (size_t)i * 8);
    f32x4 b = *reinterpret_cast<const f32x4*>(x + (size_t)i * 8 + 4);
    uint4 o;
    o.x = (uint)f2bf(a[0]) | ((uint)f2bf(a[1]) << 16);
    o.y = (uint)f2bf(a[2]) | ((uint)f2bf(a[3]) << 16);
    o.z = (uint)f2bf(b[0]) | ((uint)f2bf(b[1]) << 16);
    o.w = (uint)f2bf(b[2]) | ((uint)f2bf(b[3]) << 16);
    *reinterpret_cast<uint4*>(xb + (size_t)i * 4) = o;
  } else {
    int gidx = (bid - SCAN_B - CVT_B) * 256 + tid;  // 6144 total
    if (gidx < 4096) {
      int idx = gidx;
      int lane = idx & 63;
      int s = (idx >> 6) & 3;
      int t = idx >> 8;
      int n = t * 16 + (lane & 15);
      unsigned short v[8];
#pragma unroll
      for (int j = 0; j < 8; ++j) {
        int k = s * 32 + (j & 3) + ((lane >> 4) << 2) + ((j >> 2) << 4);
        float f = (n < DH) ? W1[(size_t)k * DH + n] : 0.f;
        v[j] = f2bf(f);
      }
      *reinterpret_cast<uint4*>(B1p + (size_t)idx * 8) =
          *reinterpret_cast<const uint4*>(v);
    } else if (gidx < 6144) {
      int idx = gidx - 4096;
      int lane = idx & 63;
      int s = (idx >> 6) & 7;
      int t = idx >> 9;
      int n = t * 16 + (lane & 15);
      unsigned short v[8];
#pragma unroll
      for (int j = 0; j < 8; ++j) {
        int k = s * 32 + (j & 3) + ((lane >> 4) << 2) + ((j >> 2) << 4);
        float f = (k < DH) ? W2[(size_t)k * DO + n] : 0.f;
        v[j] = f2bf(f);
      }
      *reinterpret_cast<uint4*>(B2p + (size_t)idx * 8) =
          *reinterpret_cast<const uint4*>(v);
    }
  }
}

// ---------------- phase C: rank + scatter (single-writer segments) ---------
__global__ __launch_bounds__(512) void k_scatC(const int* __restrict__ row,
                                               const int* __restrict__ col,
                                               const float* __restrict__ val,
                                               const int* __restrict__ hist,
                                               uint2* __restrict__ ep) {
  __shared__ int lh[NBUCK];
  __shared__ int lbase[NBUCK];
  const int tid = threadIdx.x;
  const int e0 = blockIdx.x * EPB;
  const int* hrow = hist + (size_t)blockIdx.x * NBUCK;
  for (int j = tid; j < NBUCK; j += 512) { lh[j] = 0; lbase[j] = hrow[j]; }
  __syncthreads();
#pragma unroll
  for (int p = 0; p < EPB / 512; ++p) {
    int e = e0 + p * 512 + tid;
    if (e < NE) {
      int r = row[e];
      int k = r >> 5;
      int rank = atomicAdd(&lh[k], 1);
      int pos = lbase[k] + rank;
      if (pos < CAP)
        ep[(size_t)k * CAP + pos] =
            make_uint2((uint)col[e] | ((uint)(r & (RPB - 1)) << 16),
                       __float_as_uint(val[e]));
    }
  }
}

// ---------------- fused SpMM + MLP: one block per 32-row bucket ------------
// (round-14 proven body, 43.4 us) 256 thr (4 waves); in-LDS counting sort
// by (row, col>>13); half-wave paired gather; MFMA MLP; LDS aliasing.
__global__ __launch_bounds__(256, 8) void k_spmm_mlp(const uint* __restrict__ xbu,
                                                     const uint2* __restrict__ ep,
                                                     const int* __restrict__ cnt,
                                                     const unsigned short* __restrict__ B1p,
                                                     const float* __restrict__ b1,
                                                     const unsigned short* __restrict__ B2p,
                                                     const float* __restrict__ b2,
                                                     float* __restrict__ out) {
  __shared__ uint2 buf2[2112];  // 16896 B
  __shared__ int deg2[NBIN], rbase2[NBIN], rpos2[NBIN];
  __shared__ int ws[4];
  uint2* se = buf2;                                       // [CAP]   8192 B
  unsigned short* hb = (unsigned short*)(buf2 + CAP);     // [32][136] 8704 B
  unsigned short* hs = (unsigned short*)buf2;             // [32][260] 16640 B (aliases se+hb)
  const int tid = threadIdx.x;
  const int bucket = blockIdx.x;
  const int r0 = bucket * RPB;
  const int w = tid >> 6, lane = tid & 63;
  const int g = lane >> 4, r16 = lane & 15;
  const int half = lane >> 5, l32 = lane & 31;

  deg2[tid] = 0;
  __syncthreads();

  int n = cnt[bucket];
  if (n > CAP) n = CAP;
  const uint2* eb = ep + (size_t)bucket * CAP;

  // load this bucket's records once into registers (4 per thread)
  uint2 rec[4];
  int key[4];
#pragma unroll
  for (int q = 0; q < 4; ++q) {
    int j = q * 256 + tid;
    rec[q] = (j < n) ? eb[j] : make_uint2(0u, 0u);
    key[q] = (int)(((rec[q].x >> 16) & (RPB - 1)) * 8 + ((rec[q].x & 0xFFFFu) >> 13));
  }
  // pass 1: per-bin counts
#pragma unroll
  for (int q = 0; q < 4; ++q)
    if (q * 256 + tid < n) atomicAdd(&deg2[key[q]], 1);
  __syncthreads();

  // block-wide exclusive scan of 256 bin counts
  {
    int v = deg2[tid];
    int incl = v;
#pragma unroll
    for (int d = 1; d < 64; d <<= 1) {
      int t = __shfl_up(incl, d, 64);
      if (lane >= d) incl += t;
    }
    if (lane == 63) ws[w] = incl;
    __syncthreads();
    if (tid == 0) {
      int s = 0;
#pragma unroll
      for (int q = 0; q < 4; ++q) { int xx = ws[q]; ws[q] = s; s += xx; }
    }
    __syncthreads();
    int excl = ws[w] + incl - v;
    rbase2[tid] = excl;
    rpos2[tid] = excl;
  }
  __syncthreads();

  // pass 2: scatter records (row, col-window)-sorted into LDS
#pragma unroll
  for (int q = 0; q < 4; ++q)
    if (q * 256 + tid < n) {
      int p = atomicAdd(&rpos2[key[q]], 1);
      se[p] = make_uint2(rec[q].x & 0xFFFFu, rec[q].y);
    }
  __syncthreads();

  // gather: wave w owns rows w, w+4, ..., w+28; half-wave edge pairing,
  // each lane loads uint2 = 4 bf16 features.
  const uint2* xb2 = reinterpret_cast<const uint2*>(xbu);
  for (int rr = w; rr < RPB; rr += 4) {
    int gr = r0 + rr;
    if (gr >= NN) {
      if (half == 0)
        *reinterpret_cast<uint2*>(&hb[rr * 136 + 4 * l32]) = make_uint2(0u, 0u);
      continue;
    }
    int s = rbase2[rr * 8];
    int en = (rr < RPB - 1) ? rbase2[(rr + 1) * 8] : n;
    float a0 = 0.f, a1 = 0.f, a2 = 0.f, a3 = 0.f;
    int j = s + half;
    for (; j + 6 < en; j += 8) {
      uint2 e[4], qv[4];
#pragma unroll
      for (int t = 0; t < 4; ++t) e[t] = se[j + 2 * t];
#pragma unroll
      for (int t = 0; t < 4; ++t) qv[t] = xb2[(size_t)e[t].x * 32 + l32];
#pragma unroll
      for (int t = 0; t < 4; ++t) {
        float v = __uint_as_float(e[t].y);
        a0 += v * bf2f((unsigned short)qv[t].x);
        a1 += v * bf2f((unsigned short)(qv[t].x >> 16));
        a2 += v * bf2f((unsigned short)qv[t].y);
        a3 += v * bf2f((unsigned short)(qv[t].y >> 16));
      }
    }
    for (; j < en; j += 2) {
      uint2 e0 = se[j];
      uint2 q0 = xb2[(size_t)e0.x * 32 + l32];
      float v0 = __uint_as_float(e0.y);
      a0 += v0 * bf2f((unsigned short)q0.x);
      a1 += v0 * bf2f((unsigned short)(q0.x >> 16));
      a2 += v0 * bf2f((unsigned short)q0.y);
      a3 += v0 * bf2f((unsigned short)(q0.y >> 16));
    }
    // merge the two half-wave partials
    a0 += __shfl_xor(a0, 32, 64);
    a1 += __shfl_xor(a1, 32, 64);
    a2 += __shfl_xor(a2, 32, 64);
    a3 += __shfl_xor(a3, 32, 64);
    // + x self
    uint2 xs = xb2[(size_t)gr * 32 + l32];
    a0 += bf2f((unsigned short)xs.x);
    a1 += bf2f((unsigned short)(xs.x >> 16));
    a2 += bf2f((unsigned short)xs.y);
    a3 += bf2f((unsigned short)(xs.y >> 16));
    if (half == 0) {
      uint2 o;
      o.x = (uint)f2bf(a0) | ((uint)f2bf(a1) << 16);
      o.y = (uint)f2bf(a2) | ((uint)f2bf(a3) << 16);
      *reinterpret_cast<uint2*>(&hb[rr * 136 + 4 * l32]) = o;
    }
  }
  __syncthreads();   // hb ready; se dead from here on

  // ---- stage 1: hs = relu(hb @ W1 + b1); wave w = n-tiles w*4..w*4+3 ------
  f32x4 acc[2][4];
#pragma unroll
  for (int a = 0; a < 2; ++a)
#pragma unroll
    for (int b = 0; b < 4; ++b)
#pragma unroll
      for (int c = 0; c < 4; ++c) acc[a][b][c] = 0.f;

  for (int s = 0; s < 4; ++s) {
    bf16x8 af[2];
#pragma unroll
    for (int mr = 0; mr < 2; ++mr) {
      const unsigned short* p = &hb[(mr * 16 + r16) * 136 + s * 32 + g * 4];
      s16x4 lo4 = *reinterpret_cast<const s16x4*>(p);
      s16x4 hi4 = *reinterpret_cast<const s16x4*>(p + 16);
#pragma unroll
      for (int j = 0; j < 4; ++j) { af[mr][j] = lo4[j]; af[mr][4 + j] = hi4[j]; }
    }
#pragma unroll
    for (int nr = 0; nr < 4; ++nr) {
      int t = w * 4 + nr;
      bf16x8 bf = *reinterpret_cast<const bf16x8*>(B1p + (size_t)((t * 4 + s) * 64 + lane) * 8);
      acc[0][nr] = __builtin_amdgcn_mfma_f32_16x16x32_bf16(af[0], bf, acc[0][nr], 0, 0, 0);
      acc[1][nr] = __builtin_amdgcn_mfma_f32_16x16x32_bf16(af[1], bf, acc[1][nr], 0, 0, 0);
    }
  }
  __syncthreads();   // all hb reads done; hs may now overwrite se+hb
#pragma unroll
  for (int mr = 0; mr < 2; ++mr)
#pragma unroll
    for (int nr = 0; nr < 4; ++nr) {
      int nn = w * 64 + nr * 16 + r16;
      float bias = (nn < DH) ? b1[nn] : 0.f;
#pragma unroll
      for (int i = 0; i < 4; ++i) {
        int rl = mr * 16 + g * 4 + i;
        float v = acc[mr][nr][i] + bias;
        v = v > 0.f ? v : 0.f;
        if (nn >= DH) v = 0.f;
        hs[rl * 260 + nn] = f2bf(v);
      }
    }
  __syncthreads();

  // ---- stage 2: out = hs @ W2 + b2; wave w = n-tile w, m-tiles 0..1 -------
  f32x4 acc2[2];
#pragma unroll
  for (int b = 0; b < 2; ++b)
#pragma unroll
    for (int c = 0; c < 4; ++c) acc2[b][c] = 0.f;

  for (int s = 0; s < 8; ++s) {
#pragma unroll
    for (int mt = 0; mt < 2; ++mt) {
      const unsigned short* p = &hs[(mt * 16 + r16) * 260 + s * 32 + g * 4];
      s16x4 lo4 = *reinterpret_cast<const s16x4*>(p);
      s16x4 hi4 = *reinterpret_cast<const s16x4*>(p + 16);
      bf16x8 af;
#pragma unroll
      for (int j = 0; j < 4; ++j) { af[j] = lo4[j]; af[4 + j] = hi4[j]; }
      bf16x8 bf = *reinterpret_cast<const bf16x8*>(B2p + (size_t)((w * 8 + s) * 64 + lane) * 8);
      acc2[mt] = __builtin_amdgcn_mfma_f32_16x16x32_bf16(af, bf, acc2[mt], 0, 0, 0);
    }
  }
#pragma unroll
  for (int mt = 0; mt < 2; ++mt) {
    int nn = w * 16 + r16;
    float bias = b2[nn];
#pragma unroll
    for (int i = 0; i < 4; ++i) {
      int grow = r0 + mt * 16 + g * 4 + i;
      if (grow < NN) out[(size_t)grow * DO + nn] = acc2[mt][i] + bias;
    }
  }
}

extern "C" void kernel_launch(void* const* d_in, const int* in_sizes, int n_in,
                              void* d_out, int out_size, void* d_ws, size_t ws_size,
                              hipStream_t stream) {
  const float* x = (const float*)d_in[0];
  const int* erow = (const int*)d_in[1];
  const int* ecol = (const int*)d_in[2];
  const float* eval_ = (const float*)d_in[3];
  const float* W1 = (const float*)d_in[4];
  const float* b1 = (const float*)d_in[5];
  const float* W2 = (const float*)d_in[6];
  const float* b2 = (const float*)d_in[7];
  float* out = (float*)d_out;

  char* ws = (char*)d_ws;
  size_t o = 0;
  uint* xb = (uint*)(ws + o);          o += (size_t)NN * 64 * 4;   // x bf16, 12.8 MB
  unsigned short* B1p = (unsigned short*)(ws + o); o += 32768 * 2; // 64 KB
  unsigned short* B2p = (unsigned short*)(ws + o); o += 16384 * 2; // 32 KB
  o = (o + 255) & ~(size_t)255;
  int* cnt = (int*)(ws + o);           o += (NBUCK * 4 + 255) & ~(size_t)255;
  int* hist = (int*)(ws + o);          o += (size_t)NBLK_E * NBUCK * 4;  // 613 KB
  o = (o + 255) & ~(size_t)255;
  uint2* ep = (uint2*)(ws + o);        // NBUCK*CAP*8 = 12.8 MB

  k_hist<<<NBLK_E, 512, 0, stream>>>(erow, hist);
  k_scan_cvt_pack<<<SCAN_B + CVT_B + PACK_B, 256, 0, stream>>>(
      hist, cnt, x, xb, W1, W2, B1p, B2p);
  k_scatC<<<NBLK_E, 512, 0, stream>>>(erow, ecol, eval_, hist, ep);
  k_spmm_mlp<<<NBUCK, 256, 0, stream>>>(xb, ep, cnt, B1p, b1, B2p, b2, out);
}

// Round 20
// 74.689 us; speedup vs baseline: 1.3197x; 1.0252x over previous
//
#include <hip/hip_runtime.h>

#define NN 50000
#define NE 800000
#define DIN 128
#define DH 200
#define DHP 256   // padded hidden
#define DO 64
#define RPB 32        // rows per bucket
#define NBUCK 1564    // ceil(NN/32)
#define CAP 1024      // bucket capacity; lambda=512, sigma=22.6 -> +22 sigma
#define EPB 8192      // edges per histogram/scatter block (512 thr x 16)
#define NBLK_E ((NE + EPB - 1) / EPB)   // 98
#define SCAN_B 7      // ceil(NBUCK/256)
#define CVT_B 1563    // ceil(800000/512)
#define PACK_B 12     // 6144/512
#define NBIN 256      // row*8 + (col>>13): col-phase sub-bins

typedef float f32x4 __attribute__((ext_vector_type(4)));
typedef short bf16x8 __attribute__((ext_vector_type(8)));
typedef short s16x4 __attribute__((ext_vector_type(4)));
typedef unsigned int uint;

__device__ __forceinline__ unsigned short f2bf(float f) {
  unsigned int b = __float_as_uint(f);
  b = (b + 0x7FFFu + ((b >> 16) & 1u)) >> 16;
  return (unsigned short)b;
}
__device__ __forceinline__ float bf2f(unsigned short u) {
  return __uint_as_float((unsigned int)u << 16);
}

// ---------------- phase A: block-local bucket histogram (block-major) ------
__global__ __launch_bounds__(512) void k_hist(const int* __restrict__ row,
                                              int* __restrict__ hist) {
  __shared__ int lh[NBUCK];
  const int tid = threadIdx.x;
  const int e0 = blockIdx.x * EPB;
  for (int j = tid; j < NBUCK; j += 512) lh[j] = 0;
  __syncthreads();
#pragma unroll
  for (int p = 0; p < EPB / 512; ++p) {
    int e = e0 + p * 512 + tid;
    if (e < NE) atomicAdd(&lh[row[e] >> 5], 1);
  }
  __syncthreads();
  int* hrow = hist + (size_t)blockIdx.x * NBUCK;
  for (int j = tid; j < NBUCK; j += 512) hrow[j] = lh[j];
}

// ---------------- phase B: scan only (tiny: 7 blocks) ----------------------
__global__ __launch_bounds__(256) void k_scan(int* __restrict__ hist,
                                              int* __restrict__ cnt) {
  int k = blockIdx.x * 256 + threadIdx.x;
  if (k >= NBUCK) return;
  int run = 0;
  int b = 0;
  for (; b + 8 <= NBLK_E; b += 8) {
    int v0 = hist[(size_t)(b + 0) * NBUCK + k];
    int v1 = hist[(size_t)(b + 1) * NBUCK + k];
    int v2 = hist[(size_t)(b + 2) * NBUCK + k];
    int v3 = hist[(size_t)(b + 3) * NBUCK + k];
    int v4 = hist[(size_t)(b + 4) * NBUCK + k];
    int v5 = hist[(size_t)(b + 5) * NBUCK + k];
    int v6 = hist[(size_t)(b + 6) * NBUCK + k];
    int v7 = hist[(size_t)(b + 7) * NBUCK + k];
    hist[(size_t)(b + 0) * NBUCK + k] = run; run += v0;
    hist[(size_t)(b + 1) * NBUCK + k] = run; run += v1;
    hist[(size_t)(b + 2) * NBUCK + k] = run; run += v2;
    hist[(size_t)(b + 3) * NBUCK + k] = run; run += v3;
    hist[(size_t)(b + 4) * NBUCK + k] = run; run += v4;
    hist[(size_t)(b + 5) * NBUCK + k] = run; run += v5;
    hist[(size_t)(b + 6) * NBUCK + k] = run; run += v6;
    hist[(size_t)(b + 7) * NBUCK + k] = run; run += v7;
  }
  for (; b < NBLK_E; ++b) {
    int v = hist[(size_t)b * NBUCK + k];
    hist[(size_t)b * NBUCK + k] = run;
    run += v;
  }
  cnt[k] = run;
}

// ---------------- phase C: scatC (98) | cvt x->bf16 (1563) | pack (12) -----
// scatC depends only on scan; cvt/pack feed only the spmm launch -> they
// overlap here, filling the machine around the 98 scatter blocks.
__global__ __launch_bounds__(512) void k_scat_cvt_pack(
    const int* __restrict__ row, const int* __restrict__ col,
    const float* __restrict__ val, const int* __restrict__ hist,
    uint2* __restrict__ ep,
    const float* __restrict__ x, uint* __restrict__ xb,
    const float* __restrict__ W1, const float* __restrict__ W2,
    unsigned short* __restrict__ B1p, unsigned short* __restrict__ B2p) {
  __shared__ int lh[NBUCK];
  __shared__ int lbase[NBUCK];
  const int bid = blockIdx.x;
  const int tid = threadIdx.x;
  if (bid < NBLK_E) {
    const int e0 = bid * EPB;
    const int* hrow = hist + (size_t)bid * NBUCK;
    for (int j = tid; j < NBUCK; j += 512) { lh[j] = 0; lbase[j] = hrow[j]; }
    __syncthreads();
#pragma unroll
    for (int p = 0; p < EPB / 512; ++p) {
      int e = e0 + p * 512 + tid;
      if (e < NE) {
        int r = row[e];
        int k = r >> 5;
        int rank = atomicAdd(&lh[k], 1);
        int pos = lbase[k] + rank;
        if (pos < CAP)
          ep[(size_t)k * CAP + pos] =
              make_uint2((uint)col[e] | ((uint)(r & (RPB - 1)) << 16),
                         __float_as_uint(val[e]));
      }
    }
  } else if (bid < NBLK_E + CVT_B) {
    int i = (bid - NBLK_E) * 512 + tid;  // 800000 items, 8 floats each
    if (i < NN * DIN / 8) {
      f32x4 a = *reinterpret_cast<const f32x4*>(x + (size_t)i * 8);
      f32x4 b = *reinterpret_cast<const f32x4*>(x + (size_t)i * 8 + 4);
      uint4 o;
      o.x = (uint)f2bf(a[0]) | ((uint)f2bf(a[1]) << 16);
      o.y = (uint)f2bf(a[2]) | ((uint)f2bf(a[3]) << 16);
      o.z = (uint)f2bf(b[0]) | ((uint)f2bf(b[1]) << 16);
      o.w = (uint)f2bf(b[2]) | ((uint)f2bf(b[3]) << 16);
      *reinterpret_cast<uint4*>(xb + (size_t)i * 4) = o;
    }
  } else {
    int gidx = (bid - NBLK_E - CVT_B) * 512 + tid;  // 6144 total
    if (gidx < 4096) {
      int idx = gidx;
      int lane = idx & 63;
      int s = (idx >> 6) & 3;
      int t = idx >> 8;
      int n = t * 16 + (lane & 15);
      unsigned short v[8];
#pragma unroll
      for (int j = 0; j < 8; ++j) {
        int k = s * 32 + (j & 3) + ((lane >> 4) << 2) + ((j >> 2) << 4);
        float f = (n < DH) ? W1[(size_t)k * DH + n] : 0.f;
        v[j] = f2bf(f);
      }
      *reinterpret_cast<uint4*>(B1p + (size_t)idx * 8) =
          *reinterpret_cast<const uint4*>(v);
    } else if (gidx < 6144) {
      int idx = gidx - 4096;
      int lane = idx & 63;
      int s = (idx >> 6) & 7;
      int t = idx >> 9;
      int n = t * 16 + (lane & 15);
      unsigned short v[8];
#pragma unroll
      for (int j = 0; j < 8; ++j) {
        int k = s * 32 + (j & 3) + ((lane >> 4) << 2) + ((j >> 2) << 4);
        float f = (k < DH) ? W2[(size_t)k * DO + n] : 0.f;
        v[j] = f2bf(f);
      }
      *reinterpret_cast<uint4*>(B2p + (size_t)idx * 8) =
          *reinterpret_cast<const uint4*>(v);
    }
  }
}

// ---------------- fused SpMM + MLP: one block per 32-row bucket ------------
// (round-14 proven body, 42.1 us) 256 thr (4 waves); in-LDS counting sort
// by (row, col>>13); half-wave paired gather; MFMA MLP; LDS aliasing.
__global__ __launch_bounds__(256, 8) void k_spmm_mlp(const uint* __restrict__ xbu,
                                                     const uint2* __restrict__ ep,
                                                     const int* __restrict__ cnt,
                                                     const unsigned short* __restrict__ B1p,
                                                     const float* __restrict__ b1,
                                                     const unsigned short* __restrict__ B2p,
                                                     const float* __restrict__ b2,
                                                     float* __restrict__ out) {
  __shared__ uint2 buf2[2112];  // 16896 B
  __shared__ int deg2[NBIN], rbase2[NBIN], rpos2[NBIN];
  __shared__ int ws[4];
  uint2* se = buf2;                                       // [CAP]   8192 B
  unsigned short* hb = (unsigned short*)(buf2 + CAP);     // [32][136] 8704 B
  unsigned short* hs = (unsigned short*)buf2;             // [32][260] 16640 B (aliases se+hb)
  const int tid = threadIdx.x;
  const int bucket = blockIdx.x;
  const int r0 = bucket * RPB;
  const int w = tid >> 6, lane = tid & 63;
  const int g = lane >> 4, r16 = lane & 15;
  const int half = lane >> 5, l32 = lane & 31;

  deg2[tid] = 0;
  __syncthreads();

  int n = cnt[bucket];
  if (n > CAP) n = CAP;
  const uint2* eb = ep + (size_t)bucket * CAP;

  // load this bucket's records once into registers (4 per thread)
  uint2 rec[4];
  int key[4];
#pragma unroll
  for (int q = 0; q < 4; ++q) {
    int j = q * 256 + tid;
    rec[q] = (j < n) ? eb[j] : make_uint2(0u, 0u);
    key[q] = (int)(((rec[q].x >> 16) & (RPB - 1)) * 8 + ((rec[q].x & 0xFFFFu) >> 13));
  }
  // pass 1: per-bin counts
#pragma unroll
  for (int q = 0; q < 4; ++q)
    if (q * 256 + tid < n) atomicAdd(&deg2[key[q]], 1);
  __syncthreads();

  // block-wide exclusive scan of 256 bin counts
  {
    int v = deg2[tid];
    int incl = v;
#pragma unroll
    for (int d = 1; d < 64; d <<= 1) {
      int t = __shfl_up(incl, d, 64);
      if (lane >= d) incl += t;
    }
    if (lane == 63) ws[w] = incl;
    __syncthreads();
    if (tid == 0) {
      int s = 0;
#pragma unroll
      for (int q = 0; q < 4; ++q) { int xx = ws[q]; ws[q] = s; s += xx; }
    }
    __syncthreads();
    int excl = ws[w] + incl - v;
    rbase2[tid] = excl;
    rpos2[tid] = excl;
  }
  __syncthreads();

  // pass 2: scatter records (row, col-window)-sorted into LDS
#pragma unroll
  for (int q = 0; q < 4; ++q)
    if (q * 256 + tid < n) {
      int p = atomicAdd(&rpos2[key[q]], 1);
      se[p] = make_uint2(rec[q].x & 0xFFFFu, rec[q].y);
    }
  __syncthreads();

  // gather: wave w owns rows w, w+4, ..., w+28; half-wave edge pairing,
  // each lane loads uint2 = 4 bf16 features.
  const uint2* xb2 = reinterpret_cast<const uint2*>(xbu);
  for (int rr = w; rr < RPB; rr += 4) {
    int gr = r0 + rr;
    if (gr >= NN) {
      if (half == 0)
        *reinterpret_cast<uint2*>(&hb[rr * 136 + 4 * l32]) = make_uint2(0u, 0u);
      continue;
    }
    int s = rbase2[rr * 8];
    int en = (rr < RPB - 1) ? rbase2[(rr + 1) * 8] : n;
    float a0 = 0.f, a1 = 0.f, a2 = 0.f, a3 = 0.f;
    int j = s + half;
    for (; j + 6 < en; j += 8) {
      uint2 e[4], qv[4];
#pragma unroll
      for (int t = 0; t < 4; ++t) e[t] = se[j + 2 * t];
#pragma unroll
      for (int t = 0; t < 4; ++t) qv[t] = xb2[(size_t)e[t].x * 32 + l32];
#pragma unroll
      for (int t = 0; t < 4; ++t) {
        float v = __uint_as_float(e[t].y);
        a0 += v * bf2f((unsigned short)qv[t].x);
        a1 += v * bf2f((unsigned short)(qv[t].x >> 16));
        a2 += v * bf2f((unsigned short)qv[t].y);
        a3 += v * bf2f((unsigned short)(qv[t].y >> 16));
      }
    }
    for (; j < en; j += 2) {
      uint2 e0 = se[j];
      uint2 q0 = xb2[(size_t)e0.x * 32 + l32];
      float v0 = __uint_as_float(e0.y);
      a0 += v0 * bf2f((unsigned short)q0.x);
      a1 += v0 * bf2f((unsigned short)(q0.x >> 16));
      a2 += v0 * bf2f((unsigned short)q0.y);
      a3 += v0 * bf2f((unsigned short)(q0.y >> 16));
    }
    // merge the two half-wave partials
    a0 += __shfl_xor(a0, 32, 64);
    a1 += __shfl_xor(a1, 32, 64);
    a2 += __shfl_xor(a2, 32, 64);
    a3 += __shfl_xor(a3, 32, 64);
    // + x self
    uint2 xs = xb2[(size_t)gr * 32 + l32];
    a0 += bf2f((unsigned short)xs.x);
    a1 += bf2f((unsigned short)(xs.x >> 16));
    a2 += bf2f((unsigned short)xs.y);
    a3 += bf2f((unsigned short)(xs.y >> 16));
    if (half == 0) {
      uint2 o;
      o.x = (uint)f2bf(a0) | ((uint)f2bf(a1) << 16);
      o.y = (uint)f2bf(a2) | ((uint)f2bf(a3) << 16);
      *reinterpret_cast<uint2*>(&hb[rr * 136 + 4 * l32]) = o;
    }
  }
  __syncthreads();   // hb ready; se dead from here on

  // ---- stage 1: hs = relu(hb @ W1 + b1); wave w = n-tiles w*4..w*4+3 ------
  f32x4 acc[2][4];
#pragma unroll
  for (int a = 0; a < 2; ++a)
#pragma unroll
    for (int b = 0; b < 4; ++b)
#pragma unroll
      for (int c = 0; c < 4; ++c) acc[a][b][c] = 0.f;

  for (int s = 0; s < 4; ++s) {
    bf16x8 af[2];
#pragma unroll
    for (int mr = 0; mr < 2; ++mr) {
      const unsigned short* p = &hb[(mr * 16 + r16) * 136 + s * 32 + g * 4];
      s16x4 lo4 = *reinterpret_cast<const s16x4*>(p);
      s16x4 hi4 = *reinterpret_cast<const s16x4*>(p + 16);
#pragma unroll
      for (int j = 0; j < 4; ++j) { af[mr][j] = lo4[j]; af[mr][4 + j] = hi4[j]; }
    }
#pragma unroll
    for (int nr = 0; nr < 4; ++nr) {
      int t = w * 4 + nr;
      bf16x8 bf = *reinterpret_cast<const bf16x8*>(B1p + (size_t)((t * 4 + s) * 64 + lane) * 8);
      acc[0][nr] = __builtin_amdgcn_mfma_f32_16x16x32_bf16(af[0], bf, acc[0][nr], 0, 0, 0);
      acc[1][nr] = __builtin_amdgcn_mfma_f32_16x16x32_bf16(af[1], bf, acc[1][nr], 0, 0, 0);
    }
  }
  __syncthreads();   // all hb reads done; hs may now overwrite se+hb
#pragma unroll
  for (int mr = 0; mr < 2; ++mr)
#pragma unroll
    for (int nr = 0; nr < 4; ++nr) {
      int nn = w * 64 + nr * 16 + r16;
      float bias = (nn < DH) ? b1[nn] : 0.f;
#pragma unroll
      for (int i = 0; i < 4; ++i) {
        int rl = mr * 16 + g * 4 + i;
        float v = acc[mr][nr][i] + bias;
        v = v > 0.f ? v : 0.f;
        if (nn >= DH) v = 0.f;
        hs[rl * 260 + nn] = f2bf(v);
      }
    }
  __syncthreads();

  // ---- stage 2: out = hs @ W2 + b2; wave w = n-tile w, m-tiles 0..1 -------
  f32x4 acc2[2];
#pragma unroll
  for (int b = 0; b < 2; ++b)
#pragma unroll
    for (int c = 0; c < 4; ++c) acc2[b][c] = 0.f;

  for (int s = 0; s < 8; ++s) {
#pragma unroll
    for (int mt = 0; mt < 2; ++mt) {
      const unsigned short* p = &hs[(mt * 16 + r16) * 260 + s * 32 + g * 4];
      s16x4 lo4 = *reinterpret_cast<const s16x4*>(p);
      s16x4 hi4 = *reinterpret_cast<const s16x4*>(p + 16);
      bf16x8 af;
#pragma unroll
      for (int j = 0; j < 4; ++j) { af[j] = lo4[j]; af[4 + j] = hi4[j]; }
      bf16x8 bf = *reinterpret_cast<const bf16x8*>(B2p + (size_t)((w * 8 + s) * 64 + lane) * 8);
      acc2[mt] = __builtin_amdgcn_mfma_f32_16x16x32_bf16(af, bf, acc2[mt], 0, 0, 0);
    }
  }
#pragma unroll
  for (int mt = 0; mt < 2; ++mt) {
    int nn = w * 16 + r16;
    float bias = b2[nn];
#pragma unroll
    for (int i = 0; i < 4; ++i) {
      int grow = r0 + mt * 16 + g * 4 + i;
      if (grow < NN) out[(size_t)grow * DO + nn] = acc2[mt][i] + bias;
    }
  }
}

extern "C" void kernel_launch(void* const* d_in, const int* in_sizes, int n_in,
                              void* d_out, int out_size, void* d_ws, size_t ws_size,
                              hipStream_t stream) {
  const float* x = (const float*)d_in[0];
  const int* erow = (const int*)d_in[1];
  const int* ecol = (const int*)d_in[2];
  const float* eval_ = (const float*)d_in[3];
  const float* W1 = (const float*)d_in[4];
  const float* b1 = (const float*)d_in[5];
  const float* W2 = (const float*)d_in[6];
  const float* b2 = (const float*)d_in[7];
  float* out = (float*)d_out;

  char* ws = (char*)d_ws;
  size_t o = 0;
  uint* xb = (uint*)(ws + o);          o += (size_t)NN * 64 * 4;   // x bf16, 12.8 MB
  unsigned short* B1p = (unsigned short*)(ws + o); o += 32768 * 2; // 64 KB
  unsigned short* B2p = (unsigned short*)(ws + o); o += 16384 * 2; // 32 KB
  o = (o + 255) & ~(size_t)255;
  int* cnt = (int*)(ws + o);           o += (NBUCK * 4 + 255) & ~(size_t)255;
  int* hist = (int*)(ws + o);          o += (size_t)NBLK_E * NBUCK * 4;  // 613 KB
  o = (o + 255) & ~(size_t)255;
  uint2* ep = (uint2*)(ws + o);        // NBUCK*CAP*8 = 12.8 MB

  k_hist<<<NBLK_E, 512, 0, stream>>>(erow, hist);
  k_scan<<<SCAN_B, 256, 0, stream>>>(hist, cnt);
  k_scat_cvt_pack<<<NBLK_E + CVT_B + PACK_B, 512, 0, stream>>>(
      erow, ecol, eval_, hist, ep, x, xb, W1, W2, B1p, B2p);
  k_spmm_mlp<<<NBUCK, 256, 0, stream>>>(xb, ep, cnt, B1p, b1, B2p, b2, out);
}